// Round 19
// baseline (111.198 us; speedup 1.0000x reference)
//
#include <hip/hip_runtime.h>
#include <hip/hip_bf16.h>
#include <stdint.h>

// S5 layer on MI355X — round 19: r18 base; single change:
//   gemm23 -> REGISTER-DIRECT (no LDS, no barriers, no vmcnt sync). Each wave
//   loads its MFMA fragments straight from global (16-row x 64B-segment
//   gathers, L2-served), 12 loads + 32 MFMA per kh-phase, waves free-run.
//   K-loop split at the Xb/Ub boundary for compile-time source select.
//   All other kernels byte-identical to r18.

#define BATCH 8
#define SEQ   4096
#define DMODEL 512
#define HALF  64
#define CHUNK 64
#define NCHUNK (SEQ / CHUNK)   // 64

typedef __attribute__((ext_vector_type(8))) short short8;
typedef __attribute__((ext_vector_type(4))) float f32x4;

__device__ __forceinline__ unsigned short f2bf(float f) {
    unsigned int u = __float_as_uint(f);
    u += 0x7fffu + ((u >> 16) & 1u);
    return (unsigned short)(u >> 16);
}
__device__ __forceinline__ float bf2f(unsigned short s) {
    return __uint_as_float((unsigned)s << 16);
}

// per-thread bilinear A for pole n
__device__ __forceinline__ void poleA(const float* logLr, const float* Li_in,
                                      const float* logDelta, int n,
                                      float& Ar, float& Ai) {
    float Delta = expf(logDelta[0]);
    float llr = fminf(fmaxf(logLr[n], -10.f), 10.f);
    float Lr = -expf(llr);
    float Li = Li_in[n];
    float dr = 1.f - 0.5f * Delta * Lr;
    float di = -0.5f * Delta * Li;
    float dn = dr * dr + di * di;
    float nr = 1.f + 0.5f * Delta * Lr;
    float ni = 0.5f * Delta * Li;
    Ar = (nr * dr + ni * di) / dn;
    Ai = (ni * dr - nr * di) / dn;
}

// complex power A^e (e in [0,63])
__device__ __forceinline__ void cpow(float Ar, float Ai, int e,
                                     float& wr, float& wi) {
    wr = 1.f; wi = 0.f;
    float br = Ar, bi = Ai;
#pragma unroll
    for (int k = 0; k < 6; ++k) {
        if (e & 1) { float t = wr * br - wi * bi; wi = wr * bi + wi * br; wr = t; }
        float t2 = br * br - bi * bi; bi = 2.f * br * bi; br = t2;
        e >>= 1;
    }
}

#define GLOAD_LDS16(g, l)                                                    \
    __builtin_amdgcn_global_load_lds(                                        \
        (const __attribute__((address_space(1))) unsigned int*)(g),          \
        (__attribute__((address_space(3))) unsigned int*)(l), 16, 0, 0)

// ---------------- fused weight build: Mv (blocks 0..127) + W (128..639) ----------------
__global__ void k_build(const float* __restrict__ logLr, const float* __restrict__ Li_in,
                        const float* __restrict__ logDelta,
                        const float* __restrict__ Br, const float* __restrict__ Bi,
                        const float* __restrict__ Cr, const float* __restrict__ Ci,
                        const float* __restrict__ D,
                        unsigned short* __restrict__ Mv, unsigned short* __restrict__ W) {
    int bid = blockIdx.x;
    if (bid < 128) {
        int np = bid, p = threadIdx.x;
        if (p < DMODEL) {
            int n = np & 63;
            float Delta = expf(logDelta[0]);
            float llr = fminf(fmaxf(logLr[n], -10.f), 10.f);
            float Lr = -expf(llr);
            float Li = Li_in[n];
            float dr = 1.f - 0.5f * Delta * Lr;
            float di = -0.5f * Delta * Li;
            float dn = dr * dr + di * di;
            float sr = Delta * dr / dn;
            float si = -Delta * di / dn;
            float br = Br[n * DMODEL + p], bi = Bi[n * DMODEL + p];
            float v = (np < HALF) ? (sr * br - si * bi) : (si * br + sr * bi);
            Mv[np * DMODEL + p] = f2bf(v);
        }
    } else {
        int p = bid - 128, j = threadIdx.x;
        float v;
        if (j < HALF) v = 2.f * Cr[p * HALF + j];
        else if (j < 2 * HALF) v = -2.f * Ci[p * HALF + (j - HALF)];
        else v = D[p * DMODEL + (j - 2 * HALF)];
        W[p * 640 + j] = f2bf(v);
    }
}

// ---------------- scanCB: direct carry sum + seeded recurrence -> Xb ----------------
__global__ void k_scanCB(const unsigned short* __restrict__ Vb,
                         const float* __restrict__ E,
                         const float* __restrict__ logLr, const float* __restrict__ Li_in,
                         const float* __restrict__ logDelta,
                         unsigned short* __restrict__ Xb) {
    int tid = threadIdx.x;
    int n = tid & 63;
    int c = ((blockIdx.x & 31) << 1) + (tid >> 6);
    int b = blockIdx.x >> 5;
    float Ar, Ai;
    poleA(logLr, Li_in, logDelta, n, Ar, Ai);
    float a64r = Ar, a64i = Ai;
#pragma unroll
    for (int s = 0; s < 6; ++s) {
        float t = a64r * a64r - a64i * a64i;
        a64i = 2.f * a64r * a64i;
        a64r = t;
    }
    float xr = 0.f, xi = 0.f, wr = 1.f, wi = 0.f;
    for (int jj = 1; jj <= c; ++jj) {
        int ei = ((b * NCHUNK + (c - jj)) * 2) * HALF + n;
        float er = E[ei], ev = E[ei + 64];
        xr += wr * er - wi * ev;
        xi += wr * ev + wi * er;
        float nwr = wr * a64r - wi * a64i;
        float nwi = wr * a64i + wi * a64r;
        wr = nwr; wi = nwi;
    }
    size_t base = ((size_t)b * SEQ + (size_t)c * CHUNK) * 128 + n;
    for (int tl = 0; tl < CHUNK; ++tl) {
        float vr = bf2f(Vb[base]), vi = bf2f(Vb[base + 64]);
        float nxr = Ar * xr - Ai * xi + vr;
        float nxi = Ar * xi + Ai * xr + vi;
        xr = nxr; xi = nxi;
        Xb[base] = f2bf(xr); Xb[base + 64] = f2bf(xi);
        base += 128;
    }
}

// ---------------- GEMM1 (r18 exact): Vb, Ub, E ----------------
__global__ __launch_bounds__(512) void gemm1(const float* __restrict__ U,
                                             const unsigned short* __restrict__ Mv,
                                             unsigned short* __restrict__ Vb,
                                             unsigned short* __restrict__ Ub,
                                             const float* __restrict__ logLr,
                                             const float* __restrict__ Li_in,
                                             const float* __restrict__ logDelta,
                                             float* __restrict__ E) {
    __shared__ __align__(16) unsigned short As[64 * 32];
    __shared__ __align__(16) unsigned short Bs[128 * 32];
    __shared__ float Ered[8][2][16][2];
    const int tid = threadIdx.x;
    const int lane = tid & 63;
    const int w = tid >> 6;
    const int wm = w >> 2, wn = w & 3;
    const int l15 = lane & 15, l4 = lane >> 4;
    const int row0 = blockIdx.x * 64;
    const int srow = tid >> 3;
    const int sh = (tid & 7) * 4;

    f32x4 acc[2][2];
#pragma unroll
    for (int m = 0; m < 2; ++m)
#pragma unroll
        for (int n = 0; n < 2; ++n) acc[m][n] = (f32x4)(0.f);

    for (int k0 = 0; k0 < DMODEL; k0 += 32) {
        const float4 av = *(const float4*)(U + (size_t)(row0 + srow) * DMODEL + k0 + sh);

        __syncthreads();

        GLOAD_LDS16(Mv + (size_t)(tid >> 2) * DMODEL + k0 + (tid & 3) * 8,
                    &Bs[(w * 64) * 8]);

        uint2 wa;
        wa.x = (unsigned)f2bf(av.x) | ((unsigned)f2bf(av.y) << 16);
        wa.y = (unsigned)f2bf(av.z) | ((unsigned)f2bf(av.w) << 16);
        *(uint2*)&As[srow * 32 + sh] = wa;
        *(uint2*)&Ub[(size_t)(row0 + srow) * DMODEL + k0 + sh] = wa;

        __syncthreads();

        short8 af[2], bf[2];
#pragma unroll
        for (int m = 0; m < 2; ++m)
            af[m] = *(const short8*)&As[(wm * 32 + m * 16 + l15) * 32 + l4 * 8];
#pragma unroll
        for (int n = 0; n < 2; ++n)
            bf[n] = *(const short8*)&Bs[(wn * 32 + n * 16 + l15) * 32 + l4 * 8];
#pragma unroll
        for (int m = 0; m < 2; ++m)
#pragma unroll
            for (int n = 0; n < 2; ++n)
                acc[m][n] = __builtin_amdgcn_mfma_f32_16x16x32_bf16(af[m], bf[n], acc[m][n], 0, 0, 0);
    }

#pragma unroll
    for (int m = 0; m < 2; ++m) {
        int rbase = row0 + wm * 32 + m * 16 + l4 * 4;
#pragma unroll
        for (int n = 0; n < 2; ++n) {
            int col = wn * 32 + n * 16 + l15;
#pragma unroll
            for (int r = 0; r < 4; ++r)
                Vb[(size_t)(rbase + r) * 128 + col] = f2bf(acc[m][n][r]);
        }
    }

    {
        const int base = wm * 32 + l4 * 4;
        const int isIm = (wn >= 2);
#pragma unroll
        for (int nf = 0; nf < 2; ++nf) {
            int pole = ((wn & 1) * 32) + nf * 16 + l15;
            float Ar, Ai;
            poleA(logLr, Li_in, logDelta, pole, Ar, Ai);
            float a2r = Ar * Ar - Ai * Ai, a2i = 2.f * Ar * Ai;
            float a4r = a2r * a2r - a2i * a2i, a4i = 2.f * a2r * a2i;
            float a8r = a4r * a4r - a4i * a4i, a8i = 2.f * a4r * a4i;
            float a12r = a8r * a4r - a8i * a4i, a12i = a8r * a4i + a8i * a4r;
            float wr, wi;
            cpow(Ar, Ai, 44 - base, wr, wi);
            float s2re = 0.f, s2im = 0.f;
#pragma unroll
            for (int m = 1; m >= 0; --m) {
#pragma unroll
                for (int r = 3; r >= 0; --r) {
                    float v = acc[m][nf][r];
                    if (isIm) { s2re -= wi * v; s2im += wr * v; }
                    else      { s2re += wr * v; s2im += wi * v; }
                    float nwr = wr * Ar - wi * Ai;
                    float nwi = wr * Ai + wi * Ar;
                    wr = nwr; wi = nwi;
                }
                if (m == 1) {
                    float nwr = wr * a12r - wi * a12i;
                    float nwi = wr * a12i + wi * a12r;
                    wr = nwr; wi = nwi;
                }
            }
            s2re += __shfl_xor(s2re, 16, 64);
            s2re += __shfl_xor(s2re, 32, 64);
            s2im += __shfl_xor(s2im, 16, 64);
            s2im += __shfl_xor(s2im, 32, 64);
            if (l4 == 0) {
                Ered[w][nf][l15][0] = s2re;
                Ered[w][nf][l15][1] = s2im;
            }
        }
    }
    __syncthreads();
    if (tid < 128) {
        int p = tid & 63;
        int comp = tid >> 6;
        int wn1 = p >> 5;
        int nf = (p >> 4) & 1;
        int l = p & 15;
        float s = Ered[0 * 4 + wn1][nf][l][comp] + Ered[0 * 4 + wn1 + 2][nf][l][comp]
                + Ered[1 * 4 + wn1][nf][l][comp] + Ered[1 * 4 + wn1 + 2][nf][l][comp];
        int b = row0 >> 12;
        int c = (row0 >> 6) & 63;
        E[((b * NCHUNK + c) * 2) * HALF + comp * 64 + p] = s;
    }
}

// ---------------- GEMM23 register-direct: out = [Xb | Ub] @ W^T ----------------
// 256x256 block, 8 waves (2M x 4N), wave 128x64, acc[8][4]. NO LDS, NO barriers.
// Per kh-phase: af[8] + bf[4] fragment loads straight from global (16-row x
// 64B-segment gathers), 32 swapped-operand MFMAs. K split: Xb (4 phases),
// Ub (16 phases, #pragma unroll 4). T5 setprio kept (waves desync -> role
// diversity). T1 XCD swizzle kept. D^T epilogue with dwordx4 stores.

#define MFMA32R() do {                                                         \
    __builtin_amdgcn_s_setprio(1);                                             \
    _Pragma("unroll") for (int i_ = 0; i_ < 8; ++i_)                           \
    _Pragma("unroll") for (int j_ = 0; j_ < 4; ++j_)                           \
        acc[i_][j_] = __builtin_amdgcn_mfma_f32_16x16x32_bf16(                 \
            bf[j_], af[i_], acc[i_][j_], 0, 0, 0);                             \
    __builtin_amdgcn_s_setprio(0);                                             \
} while (0)

__global__ __launch_bounds__(512) void gemm23_reg(const unsigned short* __restrict__ Xb,
                                                  const unsigned short* __restrict__ Ub,
                                                  const unsigned short* __restrict__ W,
                                                  float* __restrict__ C) {
    const int tid = threadIdx.x;
    const int lane = tid & 63;
    const int w = tid >> 6;             // 0..7
    const int wm = w >> 2, wn = w & 3;  // 2 x 4
    const int l15 = lane & 15, l4 = lane >> 4;

    // T1: bijective XCD swizzle over 256 blocks
    int lin = blockIdx.y * gridDim.x + blockIdx.x;  // 0..255
    int sw = (lin & 7) * 32 + (lin >> 3);
    const int row0 = (sw & 127) * 256;
    const int col0 = (sw >> 7) * 256;

    f32x4 acc[8][4];
#pragma unroll
    for (int m = 0; m < 8; ++m)
#pragma unroll
        for (int n = 0; n < 4; ++n) acc[m][n] = (f32x4)(0.f);

    // per-thread fragment base pointers
    const unsigned short* aX = Xb + (size_t)(row0 + wm * 128 + l15) * 128 + l4 * 8;
    const unsigned short* aU = Ub + (size_t)(row0 + wm * 128 + l15) * 512 + l4 * 8;
    const unsigned short* bW = W + (size_t)(col0 + wn * 64 + l15) * 640 + l4 * 8;

    short8 af[8], bf[4];

    // ---- Xb part: K = 0..127, 4 kh-phases ----
#pragma unroll
    for (int p = 0; p < 4; ++p) {
        const int kcol = p * 32;
#pragma unroll
        for (int i = 0; i < 8; ++i)
            af[i] = *(const short8*)(aX + i * (16 * 128) + kcol);
#pragma unroll
        for (int j = 0; j < 4; ++j)
            bf[j] = *(const short8*)(bW + j * (16 * 640) + kcol);
        MFMA32R();
    }

    // ---- Ub part: K = 128..639, 16 kh-phases ----
#pragma unroll 4
    for (int p = 0; p < 16; ++p) {
        const int kcol = p * 32;
#pragma unroll
        for (int i = 0; i < 8; ++i)
            af[i] = *(const short8*)(aU + i * (16 * 512) + kcol);
#pragma unroll
        for (int j = 0; j < 4; ++j)
            bf[j] = *(const short8*)(bW + j * (16 * 640) + 128 + kcol);
        MFMA32R();
    }

    // epilogue: D^T layout -> reg r = out-col offset; dwordx4 stores
#pragma unroll
    for (int i = 0; i < 8; ++i) {
        int row = row0 + wm * 128 + i * 16 + l15;
#pragma unroll
        for (int j = 0; j < 4; ++j) {
            int col = col0 + wn * 64 + j * 16 + l4 * 4;
            *(float4*)&C[(size_t)row * DMODEL + col] =
                make_float4(acc[i][j][0], acc[i][j][1], acc[i][j][2], acc[i][j][3]);
        }
    }
}

// ---------------- launch ----------------

extern "C" void kernel_launch(void* const* d_in, const int* in_sizes, int n_in,
                              void* d_out, int out_size, void* d_ws, size_t ws_size,
                              hipStream_t stream) {
    const float* u      = (const float*)d_in[0];
    const float* logLr  = (const float*)d_in[1];
    const float* Li     = (const float*)d_in[2];
    const float* Br     = (const float*)d_in[3];
    const float* Bi     = (const float*)d_in[4];
    const float* Cr     = (const float*)d_in[5];
    const float* Ci     = (const float*)d_in[6];
    const float* D      = (const float*)d_in[7];
    const float* logDel = (const float*)d_in[8];
    float* out = (float*)d_out;

    const size_t M = (size_t)BATCH * SEQ;  // 32768
    unsigned short* Vb = (unsigned short*)d_ws;       // M*128
    unsigned short* Ub = Vb + M * 128;                // M*512
    unsigned short* Xb = Ub + M * 512;                // M*128
    unsigned short* Mv = Xb + M * 128;                // 128*512
    unsigned short* W  = Mv + 128 * 512;              // 512*640
    float* E     = (float*)(W + 512 * 640);           // 65536

    // fused weight build (Mv + W)
    hipLaunchKernelGGL(k_build, dim3(640), dim3(640), 0, stream,
                       logLr, Li, logDel, Br, Bi, Cr, Ci, D, Mv, W);

    // GEMM1: Vb = bf16(U @ Mv^T), Ub = bf16(U), E = chunk-end states (fused)
    hipLaunchKernelGGL(gemm1, dim3(M / 64), dim3(512), 0, stream,
                       u, Mv, Vb, Ub, logLr, Li, logDel, E);

    // scan: fused exact carry + seeded recurrence -> Xb
    hipLaunchKernelGGL(k_scanCB, dim3(256), dim3(128), 0, stream,
                       Vb, E, logLr, Li, logDel, Xb);

    // GEMM23: out = [Xb | Ub] @ W^T (register-direct, no LDS/barriers)
    hipLaunchKernelGGL(gemm23_reg, dim3(M / 256, DMODEL / 256), dim3(512), 0, stream,
                       Xb, Ub, W, out);
}

// Round 20
// 78.240 us; speedup vs baseline: 1.4213x; 1.4213x over previous
//
#include <hip/hip_runtime.h>
#include <hip/hip_bf16.h>
#include <stdint.h>

// S5 layer on MI355X — round 20: byte-exact revert to round 18 (best verified,
// 78.03 us). r19's register-direct gemm23 regressed 38 -> 67 us (per-wave
// fragment gathers are L2-latency-bound without LDS load-sharing) — decisive
// evidence the LDS-ring lockstep structure is the local optimum for gemm23.
// Structure:
//   k_build : fused Mv + W weight build
//   gemm1   : 64x128 tile, 8 waves, gload_lds B, reg-staged A; Vb/Ub bf16 +
//             E chunk-end states via fused weighted-reduction epilogue
//   scanCB  : exact carry sum over E + seeded 64-step recurrence -> Xb
//   gemm23  : 256x256, BK=32 kh-phases, 4-slot LDS ring, dist-3 prefetch,
//             counted vmcnt(8), T2 swizzle, T5 setprio, T1 XCD swizzle,
//             swapped-operand MFMA (D^T) -> dwordx4 C stores.

#define BATCH 8
#define SEQ   4096
#define DMODEL 512
#define HALF  64
#define CHUNK 64
#define NCHUNK (SEQ / CHUNK)   // 64
#define NT    10               // 640/64 K-tiles in gemm23 (20 kh-phases)

typedef __attribute__((ext_vector_type(8))) short short8;
typedef __attribute__((ext_vector_type(4))) float f32x4;

__device__ __forceinline__ unsigned short f2bf(float f) {
    unsigned int u = __float_as_uint(f);
    u += 0x7fffu + ((u >> 16) & 1u);
    return (unsigned short)(u >> 16);
}
__device__ __forceinline__ float bf2f(unsigned short s) {
    return __uint_as_float((unsigned)s << 16);
}

// per-thread bilinear A for pole n
__device__ __forceinline__ void poleA(const float* logLr, const float* Li_in,
                                      const float* logDelta, int n,
                                      float& Ar, float& Ai) {
    float Delta = expf(logDelta[0]);
    float llr = fminf(fmaxf(logLr[n], -10.f), 10.f);
    float Lr = -expf(llr);
    float Li = Li_in[n];
    float dr = 1.f - 0.5f * Delta * Lr;
    float di = -0.5f * Delta * Li;
    float dn = dr * dr + di * di;
    float nr = 1.f + 0.5f * Delta * Lr;
    float ni = 0.5f * Delta * Li;
    Ar = (nr * dr + ni * di) / dn;
    Ai = (ni * dr - nr * di) / dn;
}

// complex power A^e (e in [0,63])
__device__ __forceinline__ void cpow(float Ar, float Ai, int e,
                                     float& wr, float& wi) {
    wr = 1.f; wi = 0.f;
    float br = Ar, bi = Ai;
#pragma unroll
    for (int k = 0; k < 6; ++k) {
        if (e & 1) { float t = wr * br - wi * bi; wi = wr * bi + wi * br; wr = t; }
        float t2 = br * br - bi * bi; bi = 2.f * br * bi; br = t2;
        e >>= 1;
    }
}

#define GLOAD_LDS16(g, l)                                                    \
    __builtin_amdgcn_global_load_lds(                                        \
        (const __attribute__((address_space(1))) unsigned int*)(g),          \
        (__attribute__((address_space(3))) unsigned int*)(l), 16, 0, 0)

// ---------------- fused weight build: Mv (blocks 0..127) + W (128..639) ----------------
__global__ void k_build(const float* __restrict__ logLr, const float* __restrict__ Li_in,
                        const float* __restrict__ logDelta,
                        const float* __restrict__ Br, const float* __restrict__ Bi,
                        const float* __restrict__ Cr, const float* __restrict__ Ci,
                        const float* __restrict__ D,
                        unsigned short* __restrict__ Mv, unsigned short* __restrict__ W) {
    int bid = blockIdx.x;
    if (bid < 128) {
        int np = bid, p = threadIdx.x;
        if (p < DMODEL) {
            int n = np & 63;
            float Delta = expf(logDelta[0]);
            float llr = fminf(fmaxf(logLr[n], -10.f), 10.f);
            float Lr = -expf(llr);
            float Li = Li_in[n];
            float dr = 1.f - 0.5f * Delta * Lr;
            float di = -0.5f * Delta * Li;
            float dn = dr * dr + di * di;
            float sr = Delta * dr / dn;
            float si = -Delta * di / dn;
            float br = Br[n * DMODEL + p], bi = Bi[n * DMODEL + p];
            float v = (np < HALF) ? (sr * br - si * bi) : (si * br + sr * bi);
            Mv[np * DMODEL + p] = f2bf(v);
        }
    } else {
        int p = bid - 128, j = threadIdx.x;
        float v;
        if (j < HALF) v = 2.f * Cr[p * HALF + j];
        else if (j < 2 * HALF) v = -2.f * Ci[p * HALF + (j - HALF)];
        else v = D[p * DMODEL + (j - 2 * HALF)];
        W[p * 640 + j] = f2bf(v);
    }
}

// ---------------- scanCB: direct carry sum + seeded recurrence -> Xb ----------------
__global__ void k_scanCB(const unsigned short* __restrict__ Vb,
                         const float* __restrict__ E,
                         const float* __restrict__ logLr, const float* __restrict__ Li_in,
                         const float* __restrict__ logDelta,
                         unsigned short* __restrict__ Xb) {
    int tid = threadIdx.x;
    int n = tid & 63;
    int c = ((blockIdx.x & 31) << 1) + (tid >> 6);
    int b = blockIdx.x >> 5;
    float Ar, Ai;
    poleA(logLr, Li_in, logDelta, n, Ar, Ai);
    float a64r = Ar, a64i = Ai;
#pragma unroll
    for (int s = 0; s < 6; ++s) {
        float t = a64r * a64r - a64i * a64i;
        a64i = 2.f * a64r * a64i;
        a64r = t;
    }
    float xr = 0.f, xi = 0.f, wr = 1.f, wi = 0.f;
    for (int jj = 1; jj <= c; ++jj) {
        int ei = ((b * NCHUNK + (c - jj)) * 2) * HALF + n;
        float er = E[ei], ev = E[ei + 64];
        xr += wr * er - wi * ev;
        xi += wr * ev + wi * er;
        float nwr = wr * a64r - wi * a64i;
        float nwi = wr * a64i + wi * a64r;
        wr = nwr; wi = nwi;
    }
    size_t base = ((size_t)b * SEQ + (size_t)c * CHUNK) * 128 + n;
    for (int tl = 0; tl < CHUNK; ++tl) {
        float vr = bf2f(Vb[base]), vi = bf2f(Vb[base + 64]);
        float nxr = Ar * xr - Ai * xi + vr;
        float nxi = Ar * xi + Ai * xr + vi;
        xr = nxr; xi = nxi;
        Xb[base] = f2bf(xr); Xb[base + 64] = f2bf(xi);
        base += 128;
    }
}

// ---------------- GEMM1: Vb = bf16(U @ Mv^T), Ub = bf16(U), E = chunk-end states ----------------
// 64x128 tile == one (b,chunk). K-loop r8-exact. Epilogue: Vb write + weighted
// reduction E[n] = sum_t A^{63-t} v[t][n] (in-lane + shfl + 2KB LDS exchange).
__global__ __launch_bounds__(512) void gemm1(const float* __restrict__ U,
                                             const unsigned short* __restrict__ Mv,
                                             unsigned short* __restrict__ Vb,
                                             unsigned short* __restrict__ Ub,
                                             const float* __restrict__ logLr,
                                             const float* __restrict__ Li_in,
                                             const float* __restrict__ logDelta,
                                             float* __restrict__ E) {
    __shared__ __align__(16) unsigned short As[64 * 32];
    __shared__ __align__(16) unsigned short Bs[128 * 32];
    __shared__ float Ered[8][2][16][2];   // [wave][nf][l15][re/im-target] = 2 KB
    const int tid = threadIdx.x;
    const int lane = tid & 63;
    const int w = tid >> 6;            // 0..7
    const int wm = w >> 2, wn = w & 3; // 2 x 4
    const int l15 = lane & 15, l4 = lane >> 4;
    const int row0 = blockIdx.x * 64;
    const int srow = tid >> 3;         // 0..63
    const int sh = (tid & 7) * 4;      // 0..28

    f32x4 acc[2][2];
#pragma unroll
    for (int m = 0; m < 2; ++m)
#pragma unroll
        for (int n = 0; n < 2; ++n) acc[m][n] = (f32x4)(0.f);

    for (int k0 = 0; k0 < DMODEL; k0 += 32) {
        const float4 av = *(const float4*)(U + (size_t)(row0 + srow) * DMODEL + k0 + sh);

        __syncthreads();   // prior tile's LDS reads complete

        GLOAD_LDS16(Mv + (size_t)(tid >> 2) * DMODEL + k0 + (tid & 3) * 8,
                    &Bs[(w * 64) * 8]);

        uint2 wa;
        wa.x = (unsigned)f2bf(av.x) | ((unsigned)f2bf(av.y) << 16);
        wa.y = (unsigned)f2bf(av.z) | ((unsigned)f2bf(av.w) << 16);
        *(uint2*)&As[srow * 32 + sh] = wa;
        *(uint2*)&Ub[(size_t)(row0 + srow) * DMODEL + k0 + sh] = wa;

        __syncthreads();   // vmcnt+lgkm drain: tiles staged

        short8 af[2], bf[2];
#pragma unroll
        for (int m = 0; m < 2; ++m)
            af[m] = *(const short8*)&As[(wm * 32 + m * 16 + l15) * 32 + l4 * 8];
#pragma unroll
        for (int n = 0; n < 2; ++n)
            bf[n] = *(const short8*)&Bs[(wn * 32 + n * 16 + l15) * 32 + l4 * 8];
#pragma unroll
        for (int m = 0; m < 2; ++m)
#pragma unroll
            for (int n = 0; n < 2; ++n)
                acc[m][n] = __builtin_amdgcn_mfma_f32_16x16x32_bf16(af[m], bf[n], acc[m][n], 0, 0, 0);
    }

    // ---- Vb write (raw v) ----
#pragma unroll
    for (int m = 0; m < 2; ++m) {
        int rbase = row0 + wm * 32 + m * 16 + l4 * 4;
#pragma unroll
        for (int n = 0; n < 2; ++n) {
            int col = wn * 32 + n * 16 + l15;
#pragma unroll
            for (int r = 0; r < 4; ++r)
                Vb[(size_t)(rbase + r) * 128 + col] = f2bf(acc[m][n][r]);
        }
    }

    // ---- E epilogue: weighted reduction over t ----
    {
        const int base = wm * 32 + l4 * 4;
        const int isIm = (wn >= 2);
#pragma unroll
        for (int nf = 0; nf < 2; ++nf) {
            int pole = ((wn & 1) * 32) + nf * 16 + l15;
            float Ar, Ai;
            poleA(logLr, Li_in, logDelta, pole, Ar, Ai);
            float a2r = Ar * Ar - Ai * Ai, a2i = 2.f * Ar * Ai;
            float a4r = a2r * a2r - a2i * a2i, a4i = 2.f * a2r * a2i;
            float a8r = a4r * a4r - a4i * a4i, a8i = 2.f * a4r * a4i;
            float a12r = a8r * a4r - a8i * a4i, a12i = a8r * a4i + a8i * a4r;
            float wr, wi;
            cpow(Ar, Ai, 44 - base, wr, wi);
            float s2re = 0.f, s2im = 0.f;
#pragma unroll
            for (int m = 1; m >= 0; --m) {
#pragma unroll
                for (int r = 3; r >= 0; --r) {
                    float v = acc[m][nf][r];
                    if (isIm) { s2re -= wi * v; s2im += wr * v; }
                    else      { s2re += wr * v; s2im += wi * v; }
                    float nwr = wr * Ar - wi * Ai;
                    float nwi = wr * Ai + wi * Ar;
                    wr = nwr; wi = nwi;
                }
                if (m == 1) {
                    float nwr = wr * a12r - wi * a12i;
                    float nwi = wr * a12i + wi * a12r;
                    wr = nwr; wi = nwi;
                }
            }
            s2re += __shfl_xor(s2re, 16, 64);
            s2re += __shfl_xor(s2re, 32, 64);
            s2im += __shfl_xor(s2im, 16, 64);
            s2im += __shfl_xor(s2im, 32, 64);
            if (l4 == 0) {
                Ered[w][nf][l15][0] = s2re;
                Ered[w][nf][l15][1] = s2im;
            }
        }
    }
    __syncthreads();
    if (tid < 128) {
        int p = tid & 63;           // pole
        int comp = tid >> 6;        // 0 = re, 1 = im
        int wn1 = p >> 5;
        int nf = (p >> 4) & 1;
        int l = p & 15;
        float s = Ered[0 * 4 + wn1][nf][l][comp] + Ered[0 * 4 + wn1 + 2][nf][l][comp]
                + Ered[1 * 4 + wn1][nf][l][comp] + Ered[1 * 4 + wn1 + 2][nf][l][comp];
        int b = row0 >> 12;             // batch
        int c = (row0 >> 6) & 63;       // chunk
        E[((b * NCHUNK + c) * 2) * HALF + comp * 64 + p] = s;
    }
}

// ---------------- GEMM23: out = [Xb | Ub] @ W^T, swapped-operand ----------------

#define STAGE_K(t, kh, j) do {                                                 \
    int c_ = (kh) * 1024 + (j) * 512 + tid;                                    \
    int ct_ = c_ ^ (((c_ >> 5) & 1) << 1);                                     \
    int r_ = (ct_ >> 2) & 255;                                                 \
    int kcol_ = (t) * 64 + (kh) * 32 + (ct_ & 3) * 8;                          \
    const unsigned short* asrc_ = (kcol_ < 128)                                \
        ? Xb + (size_t)(row0 + r_) * 128 + kcol_                               \
        : Ub + (size_t)(row0 + r_) * 512 + (kcol_ - 128);                      \
    GLOAD_LDS16(asrc_, &As[((t) & 1) * 16384 + ((kh) * 1024 + (j) * 512 + w * 64) * 8]); \
    GLOAD_LDS16(W + (size_t)(col0 + r_) * 640 + kcol_,                         \
                &Bs[((t) & 1) * 16384 + ((kh) * 1024 + (j) * 512 + w * 64) * 8]); \
} while (0)

#define LDAB(t, kh) do {                                                       \
    _Pragma("unroll") for (int i_ = 0; i_ < 8; ++i_) {                         \
        int r_ = wm * 128 + i_ * 16 + l15;                                     \
        int c_ = (l4 * 8) ^ (((r_ >> 3) & 1) << 4);                            \
        af[i_] = *(const short8*)&As[((t) & 1) * 16384 + (kh) * 8192 + r_ * 32 + c_]; \
    }                                                                          \
    _Pragma("unroll") for (int j_ = 0; j_ < 4; ++j_) {                         \
        int r_ = wn * 64 + j_ * 16 + l15;                                      \
        int c_ = (l4 * 8) ^ (((r_ >> 3) & 1) << 4);                            \
        bf[j_] = *(const short8*)&Bs[((t) & 1) * 16384 + (kh) * 8192 + r_ * 32 + c_]; \
    } } while (0)

// swapped operands: D^T — acc reg index = out-column offset
#define MFMA32() do {                                                          \
    __builtin_amdgcn_s_setprio(1);                                             \
    _Pragma("unroll") for (int i_ = 0; i_ < 8; ++i_)                           \
    _Pragma("unroll") for (int j_ = 0; j_ < 4; ++j_)                           \
        acc[i_][j_] = __builtin_amdgcn_mfma_f32_16x16x32_bf16(                 \
            bf[j_], af[i_], acc[i_][j_], 0, 0, 0);                             \
    __builtin_amdgcn_s_setprio(0);                                             \
} while (0)

#define PHASE_SYNC(N) do {                                                     \
    asm volatile("s_waitcnt vmcnt(" #N ")" ::: "memory");                      \
    __builtin_amdgcn_s_barrier();                                              \
    __builtin_amdgcn_sched_barrier(0);                                         \
} while (0)

__global__ __launch_bounds__(512) void gemm23_8p(const unsigned short* __restrict__ Xb,
                                                 const unsigned short* __restrict__ Ub,
                                                 const unsigned short* __restrict__ W,
                                                 float* __restrict__ C) {
    __shared__ __align__(16) unsigned short As[2 * 16384];  // 64 KiB = 4 kh-slots
    __shared__ __align__(16) unsigned short Bs[2 * 16384];  // 64 KiB
    const int tid = threadIdx.x;
    const int lane = tid & 63;
    const int w = tid >> 6;             // 0..7
    const int wm = w >> 2, wn = w & 3;  // 2 x 4
    const int l15 = lane & 15, l4 = lane >> 4;

    // T1: bijective XCD swizzle over 256 blocks
    int lin = blockIdx.y * gridDim.x + blockIdx.x;  // 0..255
    int sw = (lin & 7) * 32 + (lin >> 3);
    const int row0 = (sw & 127) * 256;
    const int col0 = (sw >> 7) * 256;

    f32x4 acc[8][4];
#pragma unroll
    for (int m = 0; m < 8; ++m)
#pragma unroll
        for (int n = 0; n < 4; ++n) acc[m][n] = (f32x4)(0.f);

    // prologue: stage kh-phases 0,1,2 (12 loads/thread in flight)
    STAGE_K(0, 0, 0); STAGE_K(0, 0, 1);
    STAGE_K(0, 1, 0); STAGE_K(0, 1, 1);
    STAGE_K(1, 0, 0); STAGE_K(1, 0, 1);

    short8 af[8], bf[4];
    for (int t = 0; t < NT - 1; ++t) {   // t = 0..8
        PHASE_SYNC(8);
        LDAB(t, 0);
        STAGE_K(t + 1, 1, 0); STAGE_K(t + 1, 1, 1);
        MFMA32();
        PHASE_SYNC(8);
        LDAB(t, 1);
        if (t < NT - 2) { STAGE_K(t + 2, 0, 0); STAGE_K(t + 2, 0, 1); }
        MFMA32();
    }
    PHASE_SYNC(4);
    LDAB(NT - 1, 0);
    MFMA32();
    PHASE_SYNC(0);
    LDAB(NT - 1, 1);
    MFMA32();

    // epilogue: D^T layout -> reg r = out-col offset; dwordx4 stores
#pragma unroll
    for (int i = 0; i < 8; ++i) {
        int row = row0 + wm * 128 + i * 16 + l15;
#pragma unroll
        for (int j = 0; j < 4; ++j) {
            int col = col0 + wn * 64 + j * 16 + l4 * 4;
            *(float4*)&C[(size_t)row * DMODEL + col] =
                make_float4(acc[i][j][0], acc[i][j][1], acc[i][j][2], acc[i][j][3]);
        }
    }
}

// ---------------- launch ----------------

extern "C" void kernel_launch(void* const* d_in, const int* in_sizes, int n_in,
                              void* d_out, int out_size, void* d_ws, size_t ws_size,
                              hipStream_t stream) {
    const float* u      = (const float*)d_in[0];
    const float* logLr  = (const float*)d_in[1];
    const float* Li     = (const float*)d_in[2];
    const float* Br     = (const float*)d_in[3];
    const float* Bi     = (const float*)d_in[4];
    const float* Cr     = (const float*)d_in[5];
    const float* Ci     = (const float*)d_in[6];
    const float* D      = (const float*)d_in[7];
    const float* logDel = (const float*)d_in[8];
    float* out = (float*)d_out;

    const size_t M = (size_t)BATCH * SEQ;  // 32768
    unsigned short* Vb = (unsigned short*)d_ws;       // M*128
    unsigned short* Ub = Vb + M * 128;                // M*512
    unsigned short* Xb = Ub + M * 512;                // M*128
    unsigned short* Mv = Xb + M * 128;                // 128*512
    unsigned short* W  = Mv + 128 * 512;              // 512*640
    float* E     = (float*)(W + 512 * 640);           // 65536

    // fused weight build (Mv + W)
    hipLaunchKernelGGL(k_build, dim3(640), dim3(640), 0, stream,
                       logLr, Li, logDel, Br, Bi, Cr, Ci, D, Mv, W);

    // GEMM1: Vb = bf16(U @ Mv^T), Ub = bf16(U), E = chunk-end states (fused)
    hipLaunchKernelGGL(gemm1, dim3(M / 64), dim3(512), 0, stream,
                       u, Mv, Vb, Ub, logLr, Li, logDel, E);

    // scan: fused exact carry + seeded recurrence -> Xb
    hipLaunchKernelGGL(k_scanCB, dim3(256), dim3(128), 0, stream,
                       Vb, E, logLr, Li, logDel, Xb);

    // GEMM23: out = [Xb | Ub] @ W^T
    hipLaunchKernelGGL(gemm23_8p, dim3(M / 256, DMODEL / 256), dim3(512), 0, stream,
                       Xb, Ub, W, out);
}

// Round 21
// 74.575 us; speedup vs baseline: 1.4911x; 1.0491x over previous
//
#include <hip/hip_runtime.h>
#include <hip/hip_bf16.h>
#include <stdint.h>

// S5 layer on MI355X — round 21: r20 base; single contained change:
//   scanCB carry loop -> 2-way interleaved accumulators (even/odd jj, weights
//   stride A^128): halves the serial weight-chain depth, doubles E-load ILP.
//   Pure sum reassociation (exact up to fp rounding). All other kernels
//   byte-identical to r20 (78.0-78.2 us verified).

#define BATCH 8
#define SEQ   4096
#define DMODEL 512
#define HALF  64
#define CHUNK 64
#define NCHUNK (SEQ / CHUNK)   // 64
#define NT    10               // 640/64 K-tiles in gemm23 (20 kh-phases)

typedef __attribute__((ext_vector_type(8))) short short8;
typedef __attribute__((ext_vector_type(4))) float f32x4;

__device__ __forceinline__ unsigned short f2bf(float f) {
    unsigned int u = __float_as_uint(f);
    u += 0x7fffu + ((u >> 16) & 1u);
    return (unsigned short)(u >> 16);
}
__device__ __forceinline__ float bf2f(unsigned short s) {
    return __uint_as_float((unsigned)s << 16);
}

// per-thread bilinear A for pole n
__device__ __forceinline__ void poleA(const float* logLr, const float* Li_in,
                                      const float* logDelta, int n,
                                      float& Ar, float& Ai) {
    float Delta = expf(logDelta[0]);
    float llr = fminf(fmaxf(logLr[n], -10.f), 10.f);
    float Lr = -expf(llr);
    float Li = Li_in[n];
    float dr = 1.f - 0.5f * Delta * Lr;
    float di = -0.5f * Delta * Li;
    float dn = dr * dr + di * di;
    float nr = 1.f + 0.5f * Delta * Lr;
    float ni = 0.5f * Delta * Li;
    Ar = (nr * dr + ni * di) / dn;
    Ai = (ni * dr - nr * di) / dn;
}

// complex power A^e (e in [0,63])
__device__ __forceinline__ void cpow(float Ar, float Ai, int e,
                                     float& wr, float& wi) {
    wr = 1.f; wi = 0.f;
    float br = Ar, bi = Ai;
#pragma unroll
    for (int k = 0; k < 6; ++k) {
        if (e & 1) { float t = wr * br - wi * bi; wi = wr * bi + wi * br; wr = t; }
        float t2 = br * br - bi * bi; bi = 2.f * br * bi; br = t2;
        e >>= 1;
    }
}

#define GLOAD_LDS16(g, l)                                                    \
    __builtin_amdgcn_global_load_lds(                                        \
        (const __attribute__((address_space(1))) unsigned int*)(g),          \
        (__attribute__((address_space(3))) unsigned int*)(l), 16, 0, 0)

// ---------------- fused weight build: Mv (blocks 0..127) + W (128..639) ----------------
__global__ void k_build(const float* __restrict__ logLr, const float* __restrict__ Li_in,
                        const float* __restrict__ logDelta,
                        const float* __restrict__ Br, const float* __restrict__ Bi,
                        const float* __restrict__ Cr, const float* __restrict__ Ci,
                        const float* __restrict__ D,
                        unsigned short* __restrict__ Mv, unsigned short* __restrict__ W) {
    int bid = blockIdx.x;
    if (bid < 128) {
        int np = bid, p = threadIdx.x;
        if (p < DMODEL) {
            int n = np & 63;
            float Delta = expf(logDelta[0]);
            float llr = fminf(fmaxf(logLr[n], -10.f), 10.f);
            float Lr = -expf(llr);
            float Li = Li_in[n];
            float dr = 1.f - 0.5f * Delta * Lr;
            float di = -0.5f * Delta * Li;
            float dn = dr * dr + di * di;
            float sr = Delta * dr / dn;
            float si = -Delta * di / dn;
            float br = Br[n * DMODEL + p], bi = Bi[n * DMODEL + p];
            float v = (np < HALF) ? (sr * br - si * bi) : (si * br + sr * bi);
            Mv[np * DMODEL + p] = f2bf(v);
        }
    } else {
        int p = bid - 128, j = threadIdx.x;
        float v;
        if (j < HALF) v = 2.f * Cr[p * HALF + j];
        else if (j < 2 * HALF) v = -2.f * Ci[p * HALF + (j - HALF)];
        else v = D[p * DMODEL + (j - 2 * HALF)];
        W[p * 640 + j] = f2bf(v);
    }
}

// ---------------- scanCB: 2-way-ILP carry sum + seeded recurrence -> Xb ----------------
__global__ void k_scanCB(const unsigned short* __restrict__ Vb,
                         const float* __restrict__ E,
                         const float* __restrict__ logLr, const float* __restrict__ Li_in,
                         const float* __restrict__ logDelta,
                         unsigned short* __restrict__ Xb) {
    int tid = threadIdx.x;
    int n = tid & 63;
    int c = ((blockIdx.x & 31) << 1) + (tid >> 6);
    int b = blockIdx.x >> 5;
    float Ar, Ai;
    poleA(logLr, Li_in, logDelta, n, Ar, Ai);
    float a64r = Ar, a64i = Ai;
#pragma unroll
    for (int s = 0; s < 6; ++s) {
        float t = a64r * a64r - a64i * a64i;
        a64i = 2.f * a64r * a64i;
        a64r = t;
    }
    // A^128 stride for the two interleaved weight chains
    float a128r = a64r * a64r - a64i * a64i;
    float a128i = 2.f * a64r * a64i;
    // carry = sum_{jj=1..c} (A^64)^(jj-1) * E_{c-jj}, split even/odd jj
    float x0r = 0.f, x0i = 0.f, x1r = 0.f, x1i = 0.f;
    float w0r = 1.f, w0i = 0.f;         // (A^64)^0 for jj = 1
    float w1r = a64r, w1i = a64i;       // (A^64)^1 for jj = 2
    const float* Eb = E + b * NCHUNK * 2 * HALF + n;
    int jj = 1;
    for (; jj + 1 <= c; jj += 2) {
        const float* e0 = Eb + (c - jj) * 2 * HALF;
        const float* e1 = Eb + (c - jj - 1) * 2 * HALF;
        float e0r = e0[0], e0v = e0[64];
        float e1r = e1[0], e1v = e1[64];
        x0r += w0r * e0r - w0i * e0v;
        x0i += w0r * e0v + w0i * e0r;
        x1r += w1r * e1r - w1i * e1v;
        x1i += w1r * e1v + w1i * e1r;
        float n0r = w0r * a128r - w0i * a128i;
        float n0i = w0r * a128i + w0i * a128r;
        w0r = n0r; w0i = n0i;
        float n1r = w1r * a128r - w1i * a128i;
        float n1i = w1r * a128i + w1i * a128r;
        w1r = n1r; w1i = n1i;
    }
    if (jj <= c) {
        const float* e0 = Eb + (c - jj) * 2 * HALF;
        float e0r = e0[0], e0v = e0[64];
        x0r += w0r * e0r - w0i * e0v;
        x0i += w0r * e0v + w0i * e0r;
    }
    float xr = x0r + x1r, xi = x0i + x1i;
    // seeded recurrence over the chunk
    size_t base = ((size_t)b * SEQ + (size_t)c * CHUNK) * 128 + n;
    for (int tl = 0; tl < CHUNK; ++tl) {
        float vr = bf2f(Vb[base]), vi = bf2f(Vb[base + 64]);
        float nxr = Ar * xr - Ai * xi + vr;
        float nxi = Ar * xi + Ai * xr + vi;
        xr = nxr; xi = nxi;
        Xb[base] = f2bf(xr); Xb[base + 64] = f2bf(xi);
        base += 128;
    }
}

// ---------------- GEMM1: Vb = bf16(U @ Mv^T), Ub = bf16(U), E = chunk-end states ----------------
__global__ __launch_bounds__(512) void gemm1(const float* __restrict__ U,
                                             const unsigned short* __restrict__ Mv,
                                             unsigned short* __restrict__ Vb,
                                             unsigned short* __restrict__ Ub,
                                             const float* __restrict__ logLr,
                                             const float* __restrict__ Li_in,
                                             const float* __restrict__ logDelta,
                                             float* __restrict__ E) {
    __shared__ __align__(16) unsigned short As[64 * 32];
    __shared__ __align__(16) unsigned short Bs[128 * 32];
    __shared__ float Ered[8][2][16][2];   // [wave][nf][l15][re/im-target] = 2 KB
    const int tid = threadIdx.x;
    const int lane = tid & 63;
    const int w = tid >> 6;            // 0..7
    const int wm = w >> 2, wn = w & 3; // 2 x 4
    const int l15 = lane & 15, l4 = lane >> 4;
    const int row0 = blockIdx.x * 64;
    const int srow = tid >> 3;         // 0..63
    const int sh = (tid & 7) * 4;      // 0..28

    f32x4 acc[2][2];
#pragma unroll
    for (int m = 0; m < 2; ++m)
#pragma unroll
        for (int n = 0; n < 2; ++n) acc[m][n] = (f32x4)(0.f);

    for (int k0 = 0; k0 < DMODEL; k0 += 32) {
        const float4 av = *(const float4*)(U + (size_t)(row0 + srow) * DMODEL + k0 + sh);

        __syncthreads();   // prior tile's LDS reads complete

        GLOAD_LDS16(Mv + (size_t)(tid >> 2) * DMODEL + k0 + (tid & 3) * 8,
                    &Bs[(w * 64) * 8]);

        uint2 wa;
        wa.x = (unsigned)f2bf(av.x) | ((unsigned)f2bf(av.y) << 16);
        wa.y = (unsigned)f2bf(av.z) | ((unsigned)f2bf(av.w) << 16);
        *(uint2*)&As[srow * 32 + sh] = wa;
        *(uint2*)&Ub[(size_t)(row0 + srow) * DMODEL + k0 + sh] = wa;

        __syncthreads();   // vmcnt+lgkm drain: tiles staged

        short8 af[2], bf[2];
#pragma unroll
        for (int m = 0; m < 2; ++m)
            af[m] = *(const short8*)&As[(wm * 32 + m * 16 + l15) * 32 + l4 * 8];
#pragma unroll
        for (int n = 0; n < 2; ++n)
            bf[n] = *(const short8*)&Bs[(wn * 32 + n * 16 + l15) * 32 + l4 * 8];
#pragma unroll
        for (int m = 0; m < 2; ++m)
#pragma unroll
            for (int n = 0; n < 2; ++n)
                acc[m][n] = __builtin_amdgcn_mfma_f32_16x16x32_bf16(af[m], bf[n], acc[m][n], 0, 0, 0);
    }

    // ---- Vb write (raw v) ----
#pragma unroll
    for (int m = 0; m < 2; ++m) {
        int rbase = row0 + wm * 32 + m * 16 + l4 * 4;
#pragma unroll
        for (int n = 0; n < 2; ++n) {
            int col = wn * 32 + n * 16 + l15;
#pragma unroll
            for (int r = 0; r < 4; ++r)
                Vb[(size_t)(rbase + r) * 128 + col] = f2bf(acc[m][n][r]);
        }
    }

    // ---- E epilogue: weighted reduction over t ----
    {
        const int base = wm * 32 + l4 * 4;
        const int isIm = (wn >= 2);
#pragma unroll
        for (int nf = 0; nf < 2; ++nf) {
            int pole = ((wn & 1) * 32) + nf * 16 + l15;
            float Ar, Ai;
            poleA(logLr, Li_in, logDelta, pole, Ar, Ai);
            float a2r = Ar * Ar - Ai * Ai, a2i = 2.f * Ar * Ai;
            float a4r = a2r * a2r - a2i * a2i, a4i = 2.f * a2r * a2i;
            float a8r = a4r * a4r - a4i * a4i, a8i = 2.f * a4r * a4i;
            float a12r = a8r * a4r - a8i * a4i, a12i = a8r * a4i + a8i * a4r;
            float wr, wi;
            cpow(Ar, Ai, 44 - base, wr, wi);
            float s2re = 0.f, s2im = 0.f;
#pragma unroll
            for (int m = 1; m >= 0; --m) {
#pragma unroll
                for (int r = 3; r >= 0; --r) {
                    float v = acc[m][nf][r];
                    if (isIm) { s2re -= wi * v; s2im += wr * v; }
                    else      { s2re += wr * v; s2im += wi * v; }
                    float nwr = wr * Ar - wi * Ai;
                    float nwi = wr * Ai + wi * Ar;
                    wr = nwr; wi = nwi;
                }
                if (m == 1) {
                    float nwr = wr * a12r - wi * a12i;
                    float nwi = wr * a12i + wi * a12r;
                    wr = nwr; wi = nwi;
                }
            }
            s2re += __shfl_xor(s2re, 16, 64);
            s2re += __shfl_xor(s2re, 32, 64);
            s2im += __shfl_xor(s2im, 16, 64);
            s2im += __shfl_xor(s2im, 32, 64);
            if (l4 == 0) {
                Ered[w][nf][l15][0] = s2re;
                Ered[w][nf][l15][1] = s2im;
            }
        }
    }
    __syncthreads();
    if (tid < 128) {
        int p = tid & 63;           // pole
        int comp = tid >> 6;        // 0 = re, 1 = im
        int wn1 = p >> 5;
        int nf = (p >> 4) & 1;
        int l = p & 15;
        float s = Ered[0 * 4 + wn1][nf][l][comp] + Ered[0 * 4 + wn1 + 2][nf][l][comp]
                + Ered[1 * 4 + wn1][nf][l][comp] + Ered[1 * 4 + wn1 + 2][nf][l][comp];
        int b = row0 >> 12;             // batch
        int c = (row0 >> 6) & 63;       // chunk
        E[((b * NCHUNK + c) * 2) * HALF + comp * 64 + p] = s;
    }
}

// ---------------- GEMM23: out = [Xb | Ub] @ W^T, swapped-operand ----------------

#define STAGE_K(t, kh, j) do {                                                 \
    int c_ = (kh) * 1024 + (j) * 512 + tid;                                    \
    int ct_ = c_ ^ (((c_ >> 5) & 1) << 1);                                     \
    int r_ = (ct_ >> 2) & 255;                                                 \
    int kcol_ = (t) * 64 + (kh) * 32 + (ct_ & 3) * 8;                          \
    const unsigned short* asrc_ = (kcol_ < 128)                                \
        ? Xb + (size_t)(row0 + r_) * 128 + kcol_                               \
        : Ub + (size_t)(row0 + r_) * 512 + (kcol_ - 128);                      \
    GLOAD_LDS16(asrc_, &As[((t) & 1) * 16384 + ((kh) * 1024 + (j) * 512 + w * 64) * 8]); \
    GLOAD_LDS16(W + (size_t)(col0 + r_) * 640 + kcol_,                         \
                &Bs[((t) & 1) * 16384 + ((kh) * 1024 + (j) * 512 + w * 64) * 8]); \
} while (0)

#define LDAB(t, kh) do {                                                       \
    _Pragma("unroll") for (int i_ = 0; i_ < 8; ++i_) {                         \
        int r_ = wm * 128 + i_ * 16 + l15;                                     \
        int c_ = (l4 * 8) ^ (((r_ >> 3) & 1) << 4);                            \
        af[i_] = *(const short8*)&As[((t) & 1) * 16384 + (kh) * 8192 + r_ * 32 + c_]; \
    }                                                                          \
    _Pragma("unroll") for (int j_ = 0; j_ < 4; ++j_) {                         \
        int r_ = wn * 64 + j_ * 16 + l15;                                      \
        int c_ = (l4 * 8) ^ (((r_ >> 3) & 1) << 4);                            \
        bf[j_] = *(const short8*)&Bs[((t) & 1) * 16384 + (kh) * 8192 + r_ * 32 + c_]; \
    } } while (0)

// swapped operands: D^T — acc reg index = out-column offset
#define MFMA32() do {                                                          \
    __builtin_amdgcn_s_setprio(1);                                             \
    _Pragma("unroll") for (int i_ = 0; i_ < 8; ++i_)                           \
    _Pragma("unroll") for (int j_ = 0; j_ < 4; ++j_)                           \
        acc[i_][j_] = __builtin_amdgcn_mfma_f32_16x16x32_bf16(                 \
            bf[j_], af[i_], acc[i_][j_], 0, 0, 0);                             \
    __builtin_amdgcn_s_setprio(0);                                             \
} while (0)

#define PHASE_SYNC(N) do {                                                     \
    asm volatile("s_waitcnt vmcnt(" #N ")" ::: "memory");                      \
    __builtin_amdgcn_s_barrier();                                              \
    __builtin_amdgcn_sched_barrier(0);                                         \
} while (0)

__global__ __launch_bounds__(512) void gemm23_8p(const unsigned short* __restrict__ Xb,
                                                 const unsigned short* __restrict__ Ub,
                                                 const unsigned short* __restrict__ W,
                                                 float* __restrict__ C) {
    __shared__ __align__(16) unsigned short As[2 * 16384];  // 64 KiB = 4 kh-slots
    __shared__ __align__(16) unsigned short Bs[2 * 16384];  // 64 KiB
    const int tid = threadIdx.x;
    const int lane = tid & 63;
    const int w = tid >> 6;             // 0..7
    const int wm = w >> 2, wn = w & 3;  // 2 x 4
    const int l15 = lane & 15, l4 = lane >> 4;

    // T1: bijective XCD swizzle over 256 blocks
    int lin = blockIdx.y * gridDim.x + blockIdx.x;  // 0..255
    int sw = (lin & 7) * 32 + (lin >> 3);
    const int row0 = (sw & 127) * 256;
    const int col0 = (sw >> 7) * 256;

    f32x4 acc[8][4];
#pragma unroll
    for (int m = 0; m < 8; ++m)
#pragma unroll
        for (int n = 0; n < 4; ++n) acc[m][n] = (f32x4)(0.f);

    // prologue: stage kh-phases 0,1,2 (12 loads/thread in flight)
    STAGE_K(0, 0, 0); STAGE_K(0, 0, 1);
    STAGE_K(0, 1, 0); STAGE_K(0, 1, 1);
    STAGE_K(1, 0, 0); STAGE_K(1, 0, 1);

    short8 af[8], bf[4];
    for (int t = 0; t < NT - 1; ++t) {   // t = 0..8
        PHASE_SYNC(8);
        LDAB(t, 0);
        STAGE_K(t + 1, 1, 0); STAGE_K(t + 1, 1, 1);
        MFMA32();
        PHASE_SYNC(8);
        LDAB(t, 1);
        if (t < NT - 2) { STAGE_K(t + 2, 0, 0); STAGE_K(t + 2, 0, 1); }
        MFMA32();
    }
    PHASE_SYNC(4);
    LDAB(NT - 1, 0);
    MFMA32();
    PHASE_SYNC(0);
    LDAB(NT - 1, 1);
    MFMA32();

    // epilogue: D^T layout -> reg r = out-col offset; dwordx4 stores
#pragma unroll
    for (int i = 0; i < 8; ++i) {
        int row = row0 + wm * 128 + i * 16 + l15;
#pragma unroll
        for (int j = 0; j < 4; ++j) {
            int col = col0 + wn * 64 + j * 16 + l4 * 4;
            *(float4*)&C[(size_t)row * DMODEL + col] =
                make_float4(acc[i][j][0], acc[i][j][1], acc[i][j][2], acc[i][j][3]);
        }
    }
}

// ---------------- launch ----------------

extern "C" void kernel_launch(void* const* d_in, const int* in_sizes, int n_in,
                              void* d_out, int out_size, void* d_ws, size_t ws_size,
                              hipStream_t stream) {
    const float* u      = (const float*)d_in[0];
    const float* logLr  = (const float*)d_in[1];
    const float* Li     = (const float*)d_in[2];
    const float* Br     = (const float*)d_in[3];
    const float* Bi     = (const float*)d_in[4];
    const float* Cr     = (const float*)d_in[5];
    const float* Ci     = (const float*)d_in[6];
    const float* D      = (const float*)d_in[7];
    const float* logDel = (const float*)d_in[8];
    float* out = (float*)d_out;

    const size_t M = (size_t)BATCH * SEQ;  // 32768
    unsigned short* Vb = (unsigned short*)d_ws;       // M*128
    unsigned short* Ub = Vb + M * 128;                // M*512
    unsigned short* Xb = Ub + M * 512;                // M*128
    unsigned short* Mv = Xb + M * 128;                // 128*512
    unsigned short* W  = Mv + 128 * 512;              // 512*640
    float* E     = (float*)(W + 512 * 640);           // 65536

    // fused weight build (Mv + W)
    hipLaunchKernelGGL(k_build, dim3(640), dim3(640), 0, stream,
                       logLr, Li, logDel, Br, Bi, Cr, Ci, D, Mv, W);

    // GEMM1: Vb = bf16(U @ Mv^T), Ub = bf16(U), E = chunk-end states (fused)
    hipLaunchKernelGGL(gemm1, dim3(M / 64), dim3(512), 0, stream,
                       u, Mv, Vb, Ub, logLr, Li, logDel, E);

    // scan: 2-way-ILP carry + seeded recurrence -> Xb
    hipLaunchKernelGGL(k_scanCB, dim3(256), dim3(128), 0, stream,
                       Vb, E, logLr, Li, logDel, Xb);

    // GEMM23: out = [Xb | Ub] @ W^T
    hipLaunchKernelGGL(gemm23_8p, dim3(M / 256, DMODEL / 256), dim3(512), 0, stream,
                       Xb, Ub, W, out);
}